// Round 6
// baseline (2242.532 us; speedup 1.0000x reference)
//
#include <hip/hip_runtime.h>

// GRU_54614804135975: 128-step GRU (B=1024,D=256,H=1024) + per-frame BatchNorm.
// Persistent kernel. R6 = R4 geometry (proven 1705us) + split barrier + BN fusion:
//  * Geometry: 512 blocks x 256 thr, 2 blocks/CU (LDS 76KB), block 64x128,
//    4 waves of 32x64, ring-3 LDS, counted vmcnt, next-step B pre-issued,
//    R4's XCD map (8-way A-line sharing; FETCH was 536MB vs R5's 1.05GB).
//  * SPLIT BARRIER (replaces full-group poll): consumer kt needs only
//    producers (mb, 2kt, 2kt+1). Tail checks flags[0..15] (gates kts 0..7)
//    with a coherent load retired by the tail's existing vmcnt(0) drain --
//    zero marginal latency, no poll loop. Flags[16..31] (kts 8..15) checked
//    mid-loop at kt=6: lagging producers get ~3us extra slack absorbed free.
//    All checks are load+vmcnt(0)+pin ADJACENT (no in-flight asm values
//    crossing iterations -> no compiler-copy staleness hazard); miss -> spin.
//    No WAR hazard exists (HH frames are write-once), so no full barrier is
//    needed -- only these RAW gates.
//  * A-issue moved into the tail (right after the low-check): HH-read latency
//    hides under the co-resident block's compute.
//  * BN stats fused into outgemm (partial sums + atomics + bnfin kernel);
//    bnstats pass deleted.

#define DEVI __device__ __forceinline__

typedef __bf16 bf16x8 __attribute__((ext_vector_type(8)));
typedef float f32x4 __attribute__((ext_vector_type(4)));
typedef unsigned int u32x4 __attribute__((ext_vector_type(4)));

typedef __attribute__((address_space(1))) const unsigned int g_u32;
typedef __attribute__((address_space(3))) unsigned int l_u32;

DEVI unsigned short f2b(float f) {
  union { float f; unsigned u; } v; v.f = f;
  return (unsigned short)((v.u + 0x7fffu + ((v.u >> 16) & 1u)) >> 16);
}

DEVI void gl_lds16(const void* g, void* s) {          // normal (L2-cached)
  __builtin_amdgcn_global_load_lds((g_u32*)g, (l_u32*)s, 16, 0, 0);
}
DEVI void st16_sc1(void* p, u32x4 v) {                // SC1 write-through to L3
  asm volatile("global_store_dwordx4 %0, %1, off sc1"
               :: "v"((unsigned long long)(__SIZE_TYPE__)p), "v"(v) : "memory");
}
DEVI unsigned ld_flag(const unsigned* p) {            // device-coherent load
  unsigned v;
  asm volatile("global_load_dword %0, %1, off sc0 sc1"
               : "=v"(v) : "v"((unsigned long long)(__SIZE_TYPE__)p) : "memory");
  return v;
}
DEVI void vm0_pin(unsigned& v) {  // retire the adjacent ld_flag, pin its value
  asm volatile("s_waitcnt vmcnt(0)" ::: "memory");
  __builtin_amdgcn_sched_barrier(0);
  asm volatile("" : "+v"(v));
}
DEVI void spin_flags(const unsigned* p, unsigned tgt) {  // rare slow path
  for (;;) {
    unsigned v = ld_flag(p);
    vm0_pin(v);
    if (__all((int)(v >= tgt))) return;
    __builtin_amdgcn_s_sleep(1);
  }
}

DEVI float sigm(float x) { return 1.0f / (1.0f + __expf(-x)); }
DEVI float tanh_f(float x) {
  float t = __expf(-2.0f * fabsf(x));
  float r = (1.0f - t) / (1.0f + t);
  return x >= 0.0f ? r : -r;
}

// ---------------- persistent GRU recurrence ----------------
// grid = 512 blocks x 256 threads, 2 blocks/CU (all co-resident; required for
// the intra-group flag waits). h crosses blocks via SC1 stores to the L3
// coherence point + first-touch plain reads -> mapping-agnostic correctness.
__global__ __launch_bounds__(256, 2) void gru_persist(
    const unsigned short* __restrict__ XB,   // 1024x256 bf16 (step-0 A)
    const unsigned short* __restrict__ WP0,  // 4096x256 bf16 n-major permuted
    const unsigned short* __restrict__ WP,   // 4096x1024 bf16 n-major permuted
    const float* __restrict__ C0v,           // step-0 gate consts [4][1024]
    const float* __restrict__ CBv,           // steady-state gate consts
    const float* __restrict__ h0,            // 1024x1024 fp32
    unsigned short* __restrict__ HH,         // history: 128 x 1024x1024 bf16
    unsigned int* __restrict__ bar)          // flags [16 groups][32 blocks]
{
  __shared__ __align__(16) unsigned short As[3][64 * 64];    // 24KB
  __shared__ __align__(16) unsigned short Bs[3][128 * 64];   // 48KB
  __shared__ __align__(16) unsigned short Hs[64 * 32];       // 4KB
  const int tid = threadIdx.x;
  const int w = tid >> 6, lane = tid & 63;
  const int wr = w >> 1, wc = w & 1;       // 2x2 wave grid, 32x64 per wave
  const int srow = lane >> 3;
  const int schunk = (lane & 7) ^ srow;    // XOR chunk swizzle
  const int l15 = lane & 15, lg = lane >> 4;
  // R4's XCD remap: xb_=b&7 encodes (mb&1, nb&3). Per XCD: 8 mb x 8 nb ->
  // B 2MB + A-slices 1MB L2-resident; 8 same-mb sharers per A-line.
  const int xb_ = blockIdx.x & 7, rb_ = blockIdx.x >> 3;     // rb_: 0..63
  const int mb = (xb_ >> 2) | ((rb_ & 7) << 1);              // 0..15
  const int nb = (xb_ & 3) | ((rb_ >> 3) << 2);              // 0..31
  const int j = nb * 32 + wc * 16 + l15;

  const float c0r = C0v[j], c0z = C0v[1024 + j], c0i = C0v[2048 + j], c0h = C0v[3072 + j];
  const float cbr = CBv[j], cbz = CBv[1024 + j], cbi = CBv[2048 + j], cbh = CBv[3072 + j];

  float hreg[2][4];
#pragma unroll
  for (int mi = 0; mi < 2; ++mi)
#pragma unroll
    for (int i = 0; i < 4; ++i)
      hreg[mi][i] = h0[(size_t)(mb * 64 + wr * 32 + mi * 16 + lg * 4 + i) * 1024 + j];

  // ---- hoisted t/kt-invariant addressing ----
  int offA[2][2], offB[2][4];
#pragma unroll
  for (int kk = 0; kk < 2; ++kk) {
#pragma unroll
    for (int mi = 0; mi < 2; ++mi) {
      int rl = wr * 32 + mi * 16 + l15;
      int slot = (kk * 4 + lg) ^ (rl & 7);
      offA[kk][mi] = rl * 128 + slot * 16;
    }
#pragma unroll
    for (int g = 0; g < 4; ++g) {
      int cl = wc * 64 + g * 16 + l15;
      int slot = (kk * 4 + lg) ^ (cl & 7);
      offB[kk][g] = cl * 128 + slot * 16;
    }
  }
  const int offq0 = srow * 1024 + schunk * 8;
  const int offq1 = (8 + srow) * 1024 + schunk * 8;
  const int offq2 = (16 + srow) * 1024 + schunk * 8;
  const int offq3 = (24 + srow) * 1024 + schunk * 8;
  const size_t arow_off = (size_t)(mb * 64 + w * 16) * 1024;
  const unsigned short* BrowS = WP + (size_t)(nb * 128 + w * 32) * 1024;
  const unsigned short* Arow0 = XB + (size_t)(mb * 64 + w * 16) * 256;
  const unsigned short* Brow0 = WP0 + (size_t)(nb * 128 + w * 32) * 256;
  const unsigned* flo = bar + mb * 32 + (lane & 15);        // flags 0..15
  const unsigned* fhi = bar + mb * 32 + 16 + (lane & 15);   // flags 16..31

// per-wave VMEM counts (vmcnt arithmetic): STAGE0=6, SSTAGE_B=4, SSTAGE_A=2.
#define STAGE0(KT, BUF)                                                       \
  _Pragma("unroll")                                                           \
  for (int q = 0; q < 4; ++q)                                                 \
    gl_lds16(Brow0 + (size_t)(q * 8 + srow) * 256 + (KT) * 64 + schunk * 8,   \
             (char*)Bs[BUF] + (w * 32 + q * 8) * 128);                        \
  _Pragma("unroll")                                                           \
  for (int q = 0; q < 2; ++q)                                                 \
    gl_lds16(Arow0 + (size_t)(q * 8 + srow) * 256 + (KT) * 64 + schunk * 8,   \
             (char*)As[BUF] + (w * 16 + q * 8) * 128);
#define SSTAGE_B(KT, BUF)                                                     \
  gl_lds16(BrowS + offq0 + (KT) * 64, (char*)Bs[BUF] + (w * 32) * 128);       \
  gl_lds16(BrowS + offq1 + (KT) * 64, (char*)Bs[BUF] + (w * 32 + 8) * 128);   \
  gl_lds16(BrowS + offq2 + (KT) * 64, (char*)Bs[BUF] + (w * 32 + 16) * 128);  \
  gl_lds16(BrowS + offq3 + (KT) * 64, (char*)Bs[BUF] + (w * 32 + 24) * 128);
#define SSTAGE_A(KT, BUF, PTR)                                                \
  gl_lds16(PTR + offq0 + (KT) * 64, (char*)As[BUF] + (w * 16) * 128);         \
  gl_lds16(PTR + offq1 + (KT) * 64, (char*)As[BUF] + (w * 16 + 8) * 128);

#define MFMA_CLUSTER                                                          \
  __builtin_amdgcn_s_setprio(1);                                              \
  {                                                                           \
    const char* Ab = (const char*)As[cur];                                    \
    const char* Bb = (const char*)Bs[cur];                                    \
    _Pragma("unroll")                                                         \
    for (int kk = 0; kk < 2; ++kk) {                                          \
      bf16x8 a[2], b[4];                                                      \
      _Pragma("unroll")                                                       \
      for (int mi = 0; mi < 2; ++mi) a[mi] = *(const bf16x8*)(Ab + offA[kk][mi]); \
      _Pragma("unroll")                                                       \
      for (int g = 0; g < 4; ++g) b[g] = *(const bf16x8*)(Bb + offB[kk][g]);  \
      _Pragma("unroll")                                                       \
      for (int mi = 0; mi < 2; ++mi)                                          \
        _Pragma("unroll")                                                     \
        for (int g = 0; g < 4; ++g)                                           \
          acc[mi][g] = __builtin_amdgcn_mfma_f32_16x16x32_bf16(               \
              a[mi], b[g], acc[mi][g], 0, 0, 0);                              \
    }                                                                         \
  }                                                                           \
  __builtin_amdgcn_s_setprio(0);

  for (int t = 0; t < 128; ++t) {
    const bool first = (t == 0);
    f32x4 acc[2][4] = {};
    int cur = 0, pre = 2;

    if (first) {
      STAGE0(0, 0)
      STAGE0(1, 1)
      for (int kt = 0; kt < 4; ++kt) {
        if (kt < 3) asm volatile("s_waitcnt vmcnt(6)" ::: "memory");
        else        asm volatile("s_waitcnt vmcnt(0)" ::: "memory");
        __builtin_amdgcn_s_barrier();
        if (kt + 2 < 4) { STAGE0(kt + 2, pre) }
        MFMA_CLUSTER
        cur = (cur == 2) ? 0 : cur + 1;
        pre = (pre == 2) ? 0 : pre + 1;
      }
    } else {
      // B0,B1 staged + A0,A1 issued at prev tail (A gated by flags 0..15).
      const unsigned short* ArowS = HH + (((size_t)(t - 1)) << 20) + arow_off;
      for (int kt = 0; kt < 16; ++kt) {
        if (kt == 0)       asm volatile("s_waitcnt vmcnt(2)" ::: "memory");
        else if (kt < 15)  asm volatile("s_waitcnt vmcnt(6)" ::: "memory");
        else               asm volatile("s_waitcnt vmcnt(0)" ::: "memory");
        __builtin_amdgcn_s_barrier();   // stage-kt data in LDS; kt-1 reads done
        if (kt == 6) {  // phase-2 gate: flags 16..31 (cover kts 8..15)
          unsigned fhv = ld_flag(fhi);
          vm0_pin(fhv);               // drains in-flight stages too (safe)
          if (!__all((int)(fhv >= (unsigned)t))) spin_flags(fhi, (unsigned)t);
        }
        if (kt + 2 < 16) { SSTAGE_B(kt + 2, pre) SSTAGE_A(kt + 2, pre, ArowS) }
        MFMA_CLUSTER
        cur = (cur == 2) ? 0 : cur + 1;
        pre = (pre == 2) ? 0 : pre + 1;
      }
    }

    // gate epilogue (4 gates of one (row,j) in one lane's 4 g-accs, via the
    // gate-permuted WP layout -- proven R2..R5)
    const float cr = first ? c0r : cbr, cz = first ? c0z : cbz;
    const float ci = first ? c0i : cbi, ch = first ? c0h : cbh;
#pragma unroll
    for (int mi = 0; mi < 2; ++mi)
#pragma unroll
      for (int i = 0; i < 4; ++i) {
        float rg = sigm(acc[mi][0][i] + cr);
        float zg = sigm(acc[mi][1][i] + cz);
        float ng = tanh_f(acc[mi][2][i] + ci + rg * (acc[mi][3][i] + ch));
        float h = (1.0f - zg) * ng + zg * hreg[mi][i];
        hreg[mi][i] = h;
        Hs[(wr * 32 + mi * 16 + lg * 4 + i) * 32 + wc * 16 + l15] = f2b(h);
      }
    __syncthreads();  // Hs complete; all waves past ALL ring-buf reads
    {  // 16B/thread: SC1 write-through of the 64x32 slice to HH[t]
      const int row = tid >> 2, part = tid & 3;
      u32x4 v = *(const u32x4*)((char*)Hs + tid * 16);
      size_t off = (size_t)(mb * 64 + row) * 1024 + nb * 32 + part * 8;
      st16_sc1(HH + ((size_t)t << 20) + off, v);
    }

    if (t != 127) {
      // Pre-issue next step's B0,B1 (h-independent; post-sync, rings free).
      SSTAGE_B(0, 0)
      SSTAGE_B(1, 1)
      // FIFO: [HHstore(1) B0(4) B1(4)] -> vmcnt(8) retires the SC1 store
      asm volatile("s_waitcnt vmcnt(8)" ::: "memory");
      __syncthreads();  // all waves' HH stores at L3 before the flag
      if (tid == 0)
        __hip_atomic_store(&bar[mb * 32 + nb], (unsigned)(t + 1),
                           __ATOMIC_RELAXED, __HIP_MEMORY_SCOPE_AGENT);
      // phase-1 gate: flags 0..15 (cover kts 0..7 of next step). The load's
      // L3 latency overlaps the B-drain we must pay anyway.
      unsigned flv = ld_flag(flo);
      vm0_pin(flv);
      if (!__all((int)(flv >= (unsigned)(t + 1)))) spin_flags(flo, (unsigned)(t + 1));
      {  // issue next step's A0,A1 now (reads HH[t], gated by the check)
        const unsigned short* ArowN = HH + ((size_t)t << 20) + arow_off;
        SSTAGE_A(0, 0, ArowN)
        SSTAGE_A(1, 1, ArowN)
      }
      // no trailing sync needed: next kt0's s_barrier synchronizes
    }
  }
#undef STAGE0
#undef SSTAGE_A
#undef SSTAGE_B
#undef MFMA_CLUSTER
}

// ---- deferred out-GEMM: out = HH @ W_lin.T + b_lin, fused BN partial sums ----
__global__ __launch_bounds__(256) void outgemm(
    const unsigned short* __restrict__ A,   // 131072 x 1024 bf16
    const unsigned short* __restrict__ Bw,  // 256 x 1024 bf16 (n-major)
    const float* __restrict__ bias,
    float* __restrict__ out,
    float* __restrict__ sumv,               // [128][256] Σ out  (zeroed)
    float* __restrict__ sumsq)              // [128][256] Σ out² (zeroed)
{
  __shared__ __align__(16) unsigned short As[128 * 64];
  __shared__ __align__(16) unsigned short Bs[128 * 64];
  const int tid = threadIdx.x;
  const int w = tid >> 6, lane = tid & 63;
  const int srow = lane >> 3, schunk = (lane & 7) ^ srow;
  const int l15 = lane & 15, lg = lane >> 4;
  const int mb = blockIdx.x >> 1, nb = blockIdx.x & 1;
  const int wr = w >> 1, wc = w & 1;
  f32x4 acc[4][4] = {};
  const unsigned short* Ag = A + (size_t)(mb * 128 + w * 32) * 1024;
  const unsigned short* Bg = Bw + (size_t)(nb * 128 + w * 32) * 1024;
  for (int kt = 0; kt < 16; ++kt) {
    const int k0 = kt * 64;
    __syncthreads();
#pragma unroll
    for (int q = 0; q < 4; ++q) {
      gl_lds16(Ag + (size_t)(q * 8 + srow) * 1024 + k0 + schunk * 8,
               (char*)As + (w * 32 + q * 8) * 128);
      gl_lds16(Bg + (size_t)(q * 8 + srow) * 1024 + k0 + schunk * 8,
               (char*)Bs + (w * 32 + q * 8) * 128);
    }
    __syncthreads();
#pragma unroll
    for (int kk = 0; kk < 2; ++kk) {
      bf16x8 a[4], b[4];
#pragma unroll
      for (int mi = 0; mi < 4; ++mi) {
        int rl = wr * 64 + mi * 16 + l15;
        int slot = (kk * 4 + lg) ^ (rl & 7);
        a[mi] = *(const bf16x8*)(As + rl * 64 + slot * 8);
      }
#pragma unroll
      for (int g = 0; g < 4; ++g) {
        int cl = g * 32 + wc * 16 + l15;
        int slot = (kk * 4 + lg) ^ (cl & 7);
        b[g] = *(const bf16x8*)(Bs + cl * 64 + slot * 8);
      }
#pragma unroll
      for (int mi = 0; mi < 4; ++mi)
#pragma unroll
        for (int g = 0; g < 4; ++g)
          acc[mi][g] = __builtin_amdgcn_mfma_f32_16x16x32_bf16(
              a[mi], b[g], acc[mi][g], 0, 0, 0);
    }
  }
  const int tf = mb >> 3;  // frame index (rows of tile are one t)
  float s[4] = {0, 0, 0, 0}, ss[4] = {0, 0, 0, 0};
#pragma unroll
  for (int mi = 0; mi < 4; ++mi)
#pragma unroll
    for (int g = 0; g < 4; ++g) {
      int d = nb * 128 + g * 32 + wc * 16 + l15;
      float bb = bias[d];
#pragma unroll
      for (int i = 0; i < 4; ++i) {
        int row = mb * 128 + wr * 64 + mi * 16 + lg * 4 + i;
        float v = acc[mi][g][i] + bb;
        out[(size_t)row * 256 + d] = v;
        s[g] += v; ss[g] += v * v;
      }
    }
  // reduce over lg (lanes l15, l15+16, l15+32, l15+48 share d)
#pragma unroll
  for (int g = 0; g < 4; ++g) {
    s[g] += __shfl_xor(s[g], 16);  s[g] += __shfl_xor(s[g], 32);
    ss[g] += __shfl_xor(ss[g], 16); ss[g] += __shfl_xor(ss[g], 32);
  }
  if (lg == 0) {
#pragma unroll
    for (int g = 0; g < 4; ++g) {
      int d = nb * 128 + g * 32 + wc * 16 + l15;
      atomicAdd(&sumv[tf * 256 + d], s[g]);
      atomicAdd(&sumsq[tf * 256 + d], ss[g]);
    }
  }
}

// ---------------- plain 128x128 GEMM (W_ih @ W_lin precompute) ----------------
__global__ __launch_bounds__(256) void gemm128(
    const unsigned short* __restrict__ A, const unsigned short* __restrict__ B,
    float* __restrict__ C, int K, int nT)
{
  __shared__ __align__(16) unsigned short As[128 * 64];
  __shared__ __align__(16) unsigned short Bs[128 * 64];
  const int tid = threadIdx.x;
  const int w = tid >> 6, lane = tid & 63;
  const int srow = lane >> 3, schunk = (lane & 7) ^ srow;
  const int l15 = lane & 15, lg = lane >> 4;
  const int mb = blockIdx.x / nT, nb = blockIdx.x % nT;
  const int wr = w >> 1, wc = w & 1;
  const int N = nT * 128;
  f32x4 acc[4][4] = {};
  const unsigned short* Ag = A + (size_t)(mb * 128 + w * 32) * K;
  const unsigned short* Bg = B + (size_t)(nb * 128 + w * 32) * K;
  for (int kt = 0; kt < (K >> 6); ++kt) {
    const int k0 = kt * 64;
    __syncthreads();
#pragma unroll
    for (int q = 0; q < 4; ++q) {
      gl_lds16(Ag + (size_t)(q * 8 + srow) * K + k0 + schunk * 8,
               (char*)As + (w * 32 + q * 8) * 128);
      gl_lds16(Bg + (size_t)(q * 8 + srow) * K + k0 + schunk * 8,
               (char*)Bs + (w * 32 + q * 8) * 128);
    }
    __syncthreads();
#pragma unroll
    for (int kk = 0; kk < 2; ++kk) {
      bf16x8 a[4], b[4];
#pragma unroll
      for (int mi = 0; mi < 4; ++mi) {
        int rl = wr * 64 + mi * 16 + l15;
        int slot = (kk * 4 + lg) ^ (rl & 7);
        a[mi] = *(const bf16x8*)(As + rl * 64 + slot * 8);
      }
#pragma unroll
      for (int g = 0; g < 4; ++g) {
        int cl = g * 32 + wc * 16 + l15;
        int slot = (kk * 4 + lg) ^ (cl & 7);
        b[g] = *(const bf16x8*)(Bs + cl * 64 + slot * 8);
      }
#pragma unroll
      for (int mi = 0; mi < 4; ++mi)
#pragma unroll
        for (int g = 0; g < 4; ++g)
          acc[mi][g] = __builtin_amdgcn_mfma_f32_16x16x32_bf16(
              a[mi], b[g], acc[mi][g], 0, 0, 0);
    }
  }
#pragma unroll
  for (int mi = 0; mi < 4; ++mi)
#pragma unroll
    for (int g = 0; g < 4; ++g)
#pragma unroll
      for (int i = 0; i < 4; ++i)
        C[(size_t)(mb * 128 + wr * 64 + mi * 16 + lg * 4 + i) * N + nb * 128 +
          g * 32 + wc * 16 + l15] = acc[mi][g][i];
}

// ---------------- small prep kernels ----------------
__global__ void castall(const float* __restrict__ x, const float* __restrict__ wih,
                        const float* __restrict__ wlin, unsigned short* __restrict__ xb,
                        unsigned short* __restrict__ wihb, unsigned short* __restrict__ wlb) {
  int i = blockIdx.x * 256 + threadIdx.x;  // grid covers 786432
  if (i < 262144) { xb[i] = f2b(x[i]); wlb[i] = f2b(wlin[i]); }
  if (i < 786432) wihb[i] = f2b(wih[i]);
}

// W_lin (256x1024) -> bf16 transpose (1024x256)
__global__ void tcast(const float* __restrict__ in, unsigned short* __restrict__ out) {
  __shared__ float t[32][33];
  int i0 = blockIdx.x * 32, d0 = blockIdx.y * 32;
  for (int r = threadIdx.y; r < 32; r += 8)
    t[r][threadIdx.x] = in[(size_t)(d0 + r) * 1024 + i0 + threadIdx.x];
  __syncthreads();
  for (int r = threadIdx.y; r < 32; r += 8)
    out[(size_t)(i0 + r) * 256 + d0 + threadIdx.x] = f2b(t[threadIdx.x][r]);
}

// Build W_big (n-major [4096][1024], gate-permuted for 64-col wave tiles)
// col layout: jt(5b) | ch(1b) | gate(2b) | c0(4b); j = jt*32 + ch*16 + c0
__global__ void asmWp(const float* __restrict__ CMT, const float* __restrict__ Whh,
                      unsigned short* __restrict__ Wp) {
  int col = blockIdx.x;
  int jt = col >> 7, L = col & 127;
  int ch = L >> 6, gate = (L >> 4) & 3, c0 = L & 15;
  int j = jt * 32 + ch * 16 + c0;
  const float* s1;
  const float* s2 = nullptr;
  if (gate == 0)      { s1 = CMT + (size_t)j * 1024;          s2 = Whh + (size_t)j * 1024; }
  else if (gate == 1) { s1 = CMT + (size_t)(1024 + j) * 1024; s2 = Whh + (size_t)(1024 + j) * 1024; }
  else if (gate == 2) { s1 = CMT + (size_t)(2048 + j) * 1024; }
  else                { s1 = Whh + (size_t)(2048 + j) * 1024; }
  unsigned short* dst = Wp + (size_t)col * 1024;
  for (int k = threadIdx.x; k < 1024; k += 256) {
    float v = s1[k] + (s2 ? s2[k] : 0.0f);
    dst[k] = f2b(v);
  }
}

// Step-0 weights: permuted W_ih.T (n-major [4096][256]), h_n group = 0
__global__ void asmWp0(const float* __restrict__ Wih, unsigned short* __restrict__ Wp0) {
  int col = blockIdx.x;
  int jt = col >> 7, L = col & 127;
  int ch = L >> 6, gate = (L >> 4) & 3, c0 = L & 15;
  int j = jt * 32 + ch * 16 + c0;
  int d = threadIdx.x;  // 256
  float v = 0.0f;
  if (gate < 3) v = Wih[(size_t)(gate * 1024 + j) * 256 + d];
  Wp0[(size_t)col * 256 + d] = f2b(v);
}

__global__ void biask(const float* __restrict__ Wih, const float* __restrict__ bih,
                      const float* __restrict__ bhh, const float* __restrict__ blin,
                      float* __restrict__ cbig, float* __restrict__ c0) {
  int j = blockIdx.x * 256 + threadIdx.x;
  if (j >= 1024) return;
  float bli[3];
  for (int g = 0; g < 3; ++g) {
    int gg = g * 1024 + j;
    float s = bih[gg];
    const float* wrow = Wih + (size_t)gg * 256;
    for (int d = 0; d < 256; ++d) s += blin[d] * wrow[d];
    bli[g] = s;
  }
  cbig[j] = bli[0] + bhh[j];
  cbig[1024 + j] = bli[1] + bhh[1024 + j];
  cbig[2048 + j] = bli[2];
  cbig[3072 + j] = bhh[2048 + j];
  c0[j] = bih[j] + bhh[j];
  c0[1024 + j] = bih[1024 + j] + bhh[1024 + j];
  c0[2048 + j] = bih[2048 + j];
  c0[3072 + j] = bhh[2048 + j];
}

// ---------------- BatchNorm finalize + normalize ----------------
__global__ void bnfin(const float* __restrict__ sv, const float* __restrict__ sq,
                      float* __restrict__ mean, float* __restrict__ rstd) {
  int i = blockIdx.x * 256 + threadIdx.x;  // 32768
  float m = sv[i] * (1.0f / 1024.0f);
  float var = sq[i] * (1.0f / 1024.0f) - m * m;
  mean[i] = m;
  rstd[i] = rsqrtf(var + 1e-5f);
}

__global__ void bnnorm(float* __restrict__ o, const float* __restrict__ mean,
                       const float* __restrict__ rstd) {
  size_t base = ((size_t)blockIdx.x * 256 + threadIdx.x) * 4;  // exact: 32768*256*4
  int t = (int)(base >> 18);
  int d = (int)(base & 255);
  float4 v = *(float4*)(o + base);
  const float* mp = mean + t * 256 + d;
  const float* rp = rstd + t * 256 + d;
  float4 r;
  r.x = (v.x - mp[0]) * rp[0];
  r.y = (v.y - mp[1]) * rp[1];
  r.z = (v.z - mp[2]) * rp[2];
  r.w = (v.w - mp[3]) * rp[3];
  *(float4*)(o + base) = r;
}

// ---------------- launch ----------------
extern "C" void kernel_launch(void* const* d_in, const int* in_sizes, int n_in,
                              void* d_out, int out_size, void* d_ws, size_t ws_size,
                              hipStream_t stream) {
  (void)in_sizes; (void)n_in; (void)out_size; (void)ws_size;
  const float* x    = (const float*)d_in[0];
  const float* h0   = (const float*)d_in[1];
  const float* Wih  = (const float*)d_in[2];
  const float* Whh  = (const float*)d_in[3];
  const float* bih  = (const float*)d_in[4];
  const float* bhh  = (const float*)d_in[5];
  const float* Wlin = (const float*)d_in[6];
  const float* blin = (const float*)d_in[7];
  float* out = (float*)d_out;

  char* ws = (char*)d_ws;
  size_t off = 0;
  auto alloc = [&](size_t bytes) {
    char* p = ws + off;
    off += (bytes + 255) & ~(size_t)255;
    return p;
  };
  unsigned short* WP   = (unsigned short*)alloc(4096ull * 1024 * 2);
  unsigned short* WP0  = (unsigned short*)alloc(4096ull * 256 * 2);
  unsigned short* WIHB = (unsigned short*)alloc(3072ull * 256 * 2);
  unsigned short* WLT  = (unsigned short*)alloc(1024ull * 256 * 2);
  unsigned short* WLB  = (unsigned short*)alloc(256ull * 1024 * 2);
  unsigned short* XB   = (unsigned short*)alloc(1024ull * 256 * 2);
  float* CMT  = (float*)alloc(3072ull * 1024 * 4);
  float* CBIG = (float*)alloc(4096 * 4);
  float* C0   = (float*)alloc(4096 * 4);
  unsigned short* HH  = (unsigned short*)alloc(128ull * 1024 * 1024 * 2);
  float* SUMV = (float*)alloc(128 * 256 * 4);
  float* SUMSQ= (float*)alloc(128 * 256 * 4);
  float* MEAN = (float*)alloc(128 * 256 * 4);
  float* RSTD = (float*)alloc(128 * 256 * 4);
  unsigned int* BAR = (unsigned int*)alloc(4096);

  (void)hipMemsetAsync(BAR, 0, 4096, stream);
  (void)hipMemsetAsync(SUMV, 0, 2 * 128 * 256 * 4, stream);  // SUMV+SUMSQ contiguous

  // precompute: casts, W_lin transpose, C_MT = W_ih @ W_lin, fused weights, biases
  castall<<<3072, 256, 0, stream>>>(x, Wih, Wlin, XB, WIHB, WLB);
  tcast<<<dim3(32, 8), dim3(32, 8), 0, stream>>>(Wlin, WLT);
  gemm128<<<192, 256, 0, stream>>>(WIHB, WLT, CMT, 256, 8);
  asmWp<<<4096, 256, 0, stream>>>(CMT, Whh, WP);
  asmWp0<<<4096, 256, 0, stream>>>(Wih, WP0);
  biask<<<4, 256, 0, stream>>>(Wih, bih, bhh, blin, CBIG, C0);

  // all 128 recurrence steps in one persistent kernel (512 blocks, 2/CU)
  gru_persist<<<512, 256, 0, stream>>>(XB, WP0, WP, C0, CBIG, h0, HH, BAR);

  // deferred frame outputs + fused BN partial sums
  outgemm<<<2048, 256, 0, stream>>>(HH, WLB, blin, out, SUMV, SUMSQ);

  // BatchNorm1d (training stats), in-place on d_out
  bnfin<<<128, 256, 0, stream>>>(SUMV, SUMSQ, MEAN, RSTD);
  bnnorm<<<32768, 256, 0, stream>>>(out, MEAN, RSTD);
}

// Round 7
// 1962.908 us; speedup vs baseline: 1.1425x; 1.1425x over previous
//
#include <hip/hip_runtime.h>

// GRU_54614804135975: 128-step GRU (B=1024,D=256,H=1024) + per-frame BatchNorm.
// R7 = CONSOLIDATION: gru_persist reverted to R4 verbatim (proven 1705us; R5/R6
// restructures both regressed it) + R6's BN fusion (proven: non-gru 318->132us).
//  * gru: 512 blocks x 256 thr, 2 blocks/CU, tile 64x128, ring-3 LDS, counted
//    vmcnt (never 0 mid-pipeline except last kt), next-step B pre-issued into
//    the tail, HH[t] SC1 write-through + plain first-touch A reads, 32-slot
//    flag array + w0-only ballot poll (drains only wave 0's FIFO).
//  * epilogue: outgemm with fused BN partial sums (atomics) + bnfin + bnnorm.
//  R6 lesson encoded: any vmcnt(0) executed by stage-carrying waves mid-step
//  destroys the pipeline (MfmaUtil 30->23). Poll must stay w0-only.

#define DEVI __device__ __forceinline__

typedef __bf16 bf16x8 __attribute__((ext_vector_type(8)));
typedef float f32x4 __attribute__((ext_vector_type(4)));
typedef unsigned int u32x4 __attribute__((ext_vector_type(4)));

typedef __attribute__((address_space(1))) const unsigned int g_u32;
typedef __attribute__((address_space(3))) unsigned int l_u32;

DEVI unsigned short f2b(float f) {
  union { float f; unsigned u; } v; v.f = f;
  return (unsigned short)((v.u + 0x7fffu + ((v.u >> 16) & 1u)) >> 16);
}

DEVI void gl_lds16(const void* g, void* s) {          // normal (L2-cached)
  __builtin_amdgcn_global_load_lds((g_u32*)g, (l_u32*)s, 16, 0, 0);
}
DEVI void st16_sc1(void* p, u32x4 v) {                // SC1 write-through to L3
  asm volatile("global_store_dwordx4 %0, %1, off sc1"
               :: "v"((unsigned long long)(__SIZE_TYPE__)p), "v"(v) : "memory");
}

DEVI float sigm(float x) { return 1.0f / (1.0f + __expf(-x)); }
DEVI float tanh_f(float x) {
  float t = __expf(-2.0f * fabsf(x));
  float r = (1.0f - t) / (1.0f + t);
  return x >= 0.0f ? r : -r;
}

// ---------------- persistent GRU recurrence (R4 verbatim) ----------------
__global__ __launch_bounds__(256, 2) void gru_persist(
    const unsigned short* __restrict__ XB,   // 1024x256 bf16 (step-0 A)
    const unsigned short* __restrict__ WP0,  // 4096x256 bf16 n-major permuted
    const unsigned short* __restrict__ WP,   // 4096x1024 bf16 n-major permuted
    const float* __restrict__ C0v,           // step-0 gate consts [4][1024]
    const float* __restrict__ CBv,           // steady-state gate consts
    const float* __restrict__ h0,            // 1024x1024 fp32
    unsigned short* __restrict__ HH,         // history: 128 x 1024x1024 bf16
    unsigned int* __restrict__ bar)          // flags [16 groups][32 blocks]
{
  __shared__ __align__(16) unsigned short As[3][64 * 64];    // 24KB
  __shared__ __align__(16) unsigned short Bs[3][128 * 64];   // 48KB
  __shared__ __align__(16) unsigned short Hs[64 * 32];       // 4KB
  const int tid = threadIdx.x;
  const int w = tid >> 6, lane = tid & 63;
  const int wr = w >> 1, wc = w & 1;       // 2x2 wave grid, 32x64 per wave
  const int srow = lane >> 3;
  const int schunk = (lane & 7) ^ srow;    // XOR chunk swizzle
  const int l15 = lane & 15, lg = lane >> 4;
  // XCD remap: xb_=b&7 encodes (mb&1, nb&3). Per XCD: 8 mb x 8 nb ->
  // B 2MB + A-slices 1MB L2-resident; 8 same-mb sharers per A-line.
  const int xb_ = blockIdx.x & 7, rb_ = blockIdx.x >> 3;     // rb_: 0..63
  const int mb = (xb_ >> 2) | ((rb_ & 7) << 1);              // 0..15
  const int nb = (xb_ & 3) | ((rb_ >> 3) << 2);              // 0..31
  const int j = nb * 32 + wc * 16 + l15;

  const float c0r = C0v[j], c0z = C0v[1024 + j], c0i = C0v[2048 + j], c0h = C0v[3072 + j];
  const float cbr = CBv[j], cbz = CBv[1024 + j], cbi = CBv[2048 + j], cbh = CBv[3072 + j];

  float hreg[2][4];
#pragma unroll
  for (int mi = 0; mi < 2; ++mi)
#pragma unroll
    for (int i = 0; i < 4; ++i)
      hreg[mi][i] = h0[(size_t)(mb * 64 + wr * 32 + mi * 16 + lg * 4 + i) * 1024 + j];

  // ---- hoisted t/kt-invariant addressing ----
  int offA[2][2], offB[2][4];
#pragma unroll
  for (int kk = 0; kk < 2; ++kk) {
#pragma unroll
    for (int mi = 0; mi < 2; ++mi) {
      int rl = wr * 32 + mi * 16 + l15;
      int slot = (kk * 4 + lg) ^ (rl & 7);
      offA[kk][mi] = rl * 128 + slot * 16;
    }
#pragma unroll
    for (int g = 0; g < 4; ++g) {
      int cl = wc * 64 + g * 16 + l15;
      int slot = (kk * 4 + lg) ^ (cl & 7);
      offB[kk][g] = cl * 128 + slot * 16;
    }
  }
  const int offq0 = srow * 1024 + schunk * 8;
  const int offq1 = (8 + srow) * 1024 + schunk * 8;
  const int offq2 = (16 + srow) * 1024 + schunk * 8;
  const int offq3 = (24 + srow) * 1024 + schunk * 8;
  const size_t arow_off = (size_t)(mb * 64 + w * 16) * 1024;
  const unsigned short* BrowS = WP + (size_t)(nb * 128 + w * 32) * 1024;
  const unsigned short* Arow0 = XB + (size_t)(mb * 64 + w * 16) * 256;
  const unsigned short* Brow0 = WP0 + (size_t)(nb * 128 + w * 32) * 256;

// per-wave VMEM counts (vmcnt arithmetic): STAGE0=6, SSTAGE_B=4, SSTAGE_A=2.
#define STAGE0(KT, BUF)                                                       \
  _Pragma("unroll")                                                           \
  for (int q = 0; q < 4; ++q)                                                 \
    gl_lds16(Brow0 + (size_t)(q * 8 + srow) * 256 + (KT) * 64 + schunk * 8,   \
             (char*)Bs[BUF] + (w * 32 + q * 8) * 128);                        \
  _Pragma("unroll")                                                           \
  for (int q = 0; q < 2; ++q)                                                 \
    gl_lds16(Arow0 + (size_t)(q * 8 + srow) * 256 + (KT) * 64 + schunk * 8,   \
             (char*)As[BUF] + (w * 16 + q * 8) * 128);
#define SSTAGE_B(KT, BUF)                                                     \
  gl_lds16(BrowS + offq0 + (KT) * 64, (char*)Bs[BUF] + (w * 32) * 128);       \
  gl_lds16(BrowS + offq1 + (KT) * 64, (char*)Bs[BUF] + (w * 32 + 8) * 128);   \
  gl_lds16(BrowS + offq2 + (KT) * 64, (char*)Bs[BUF] + (w * 32 + 16) * 128);  \
  gl_lds16(BrowS + offq3 + (KT) * 64, (char*)Bs[BUF] + (w * 32 + 24) * 128);
#define SSTAGE_A(KT, BUF)                                                     \
  gl_lds16(ArowS + offq0 + (KT) * 64, (char*)As[BUF] + (w * 16) * 128);       \
  gl_lds16(ArowS + offq1 + (KT) * 64, (char*)As[BUF] + (w * 16 + 8) * 128);

  for (int t = 0; t < 128; ++t) {
    const bool first = (t == 0);
    const int iters = first ? 4 : 16;
    const unsigned short* ArowS =
        HH + (((size_t)(first ? 0 : t - 1)) << 20) + arow_off;

    f32x4 acc[2][4] = {};

    if (first) {           // fresh prologue: stages 0,1
      STAGE0(0, 0)
      STAGE0(1, 1)
    } else {               // B0,B1 pre-issued at end of prev step; A only
      SSTAGE_A(0, 0)
      SSTAGE_A(1, 1)
    }
    int cur = 0, pre = 2;
    for (int kt = 0; kt < iters; ++kt) {
      if (kt == 0) {
        if (first) asm volatile("s_waitcnt vmcnt(6)" ::: "memory");
        else       asm volatile("s_waitcnt vmcnt(2)" ::: "memory");
      } else if (kt == iters - 1) {
        asm volatile("s_waitcnt vmcnt(0)" ::: "memory");
      } else {               // exactly one full stage (6) may stay in flight
        asm volatile("s_waitcnt vmcnt(6)" ::: "memory");
      }
      __builtin_amdgcn_s_barrier();   // raw: all waves' stage-kt data in LDS;
                                      // also: all kt-1 LDS reads retired
      if (kt + 2 < iters) {
        if (first) { STAGE0(kt + 2, pre) }
        else       { SSTAGE_B(kt + 2, pre) SSTAGE_A(kt + 2, pre) }
      }
      __builtin_amdgcn_s_setprio(1);
#pragma unroll
      for (int kk = 0; kk < 2; ++kk) {
        bf16x8 a[2], b[4];
        const char* Ab = (const char*)As[cur];
        const char* Bb = (const char*)Bs[cur];
#pragma unroll
        for (int mi = 0; mi < 2; ++mi)
          a[mi] = *(const bf16x8*)(Ab + offA[kk][mi]);
#pragma unroll
        for (int g = 0; g < 4; ++g)
          b[g] = *(const bf16x8*)(Bb + offB[kk][g]);
#pragma unroll
        for (int mi = 0; mi < 2; ++mi)
#pragma unroll
          for (int g = 0; g < 4; ++g)
            acc[mi][g] = __builtin_amdgcn_mfma_f32_16x16x32_bf16(
                a[mi], b[g], acc[mi][g], 0, 0, 0);
      }
      __builtin_amdgcn_s_setprio(0);
      cur = (cur == 2) ? 0 : cur + 1;
      pre = (pre == 2) ? 0 : pre + 1;
    }

    // gate epilogue (4 gates of one (row,j) in one lane's 4 g-accs, via the
    // gate-permuted WP layout -- proven R2..R6)
    const float cr = first ? c0r : cbr, cz = first ? c0z : cbz;
    const float ci = first ? c0i : cbi, ch = first ? c0h : cbh;
#pragma unroll
    for (int mi = 0; mi < 2; ++mi)
#pragma unroll
      for (int i = 0; i < 4; ++i) {
        float rg = sigm(acc[mi][0][i] + cr);
        float zg = sigm(acc[mi][1][i] + cz);
        float ng = tanh_f(acc[mi][2][i] + ci + rg * (acc[mi][3][i] + ch));
        float h = (1.0f - zg) * ng + zg * hreg[mi][i];
        hreg[mi][i] = h;
        Hs[(wr * 32 + mi * 16 + lg * 4 + i) * 32 + wc * 16 + l15] = f2b(h);
      }
    __syncthreads();  // Hs complete; all waves past ALL ring-buf reads
    {  // 16B/thread: SC1 write-through of the 64x32 slice to HH[t]
      const int row = tid >> 2, part = tid & 3;
      u32x4 v = *(const u32x4*)((char*)Hs + tid * 16);
      size_t off = (size_t)(mb * 64 + row) * 1024 + nb * 32 + part * 8;
      st16_sc1(HH + ((size_t)t << 20) + off, v);
    }

    if (t != 127) {
      // Pre-issue next step's B0,B1 (h-independent; post-sync, rings free).
      SSTAGE_B(0, 0)
      SSTAGE_B(1, 1)
      // FIFO: [HHstore(1) B0(4) B1(4)] -> vmcnt(8) retires the SC1 store
      asm volatile("s_waitcnt vmcnt(8)" ::: "memory");
      __syncthreads();  // all waves' HH stores at L3 before the flag
      if (tid == 0)
        __hip_atomic_store(&bar[mb * 32 + nb], (unsigned)(t + 1),
                           __ATOMIC_RELAXED, __HIP_MEMORY_SCOPE_AGENT);
      if (w == 0) {     // 32-lane parallel poll (drains only wave 0's FIFO)
        const unsigned tgt = (unsigned)(t + 1);
        for (;;) {
          unsigned v = __hip_atomic_load(&bar[mb * 32 + (lane & 31)],
                                         __ATOMIC_RELAXED,
                                         __HIP_MEMORY_SCOPE_AGENT);
          if (__all((int)(v >= tgt))) break;
          __builtin_amdgcn_s_sleep(1);
        }
      }
      __syncthreads();
    }
  }
#undef STAGE0
#undef SSTAGE_A
#undef SSTAGE_B
}

// ---- deferred out-GEMM: out = HH @ W_lin.T + b_lin, fused BN partial sums ----
__global__ __launch_bounds__(256) void outgemm(
    const unsigned short* __restrict__ A,   // 131072 x 1024 bf16
    const unsigned short* __restrict__ Bw,  // 256 x 1024 bf16 (n-major)
    const float* __restrict__ bias,
    float* __restrict__ out,
    float* __restrict__ sumv,               // [128][256] Σ out  (zeroed)
    float* __restrict__ sumsq)              // [128][256] Σ out² (zeroed)
{
  __shared__ __align__(16) unsigned short As[128 * 64];
  __shared__ __align__(16) unsigned short Bs[128 * 64];
  const int tid = threadIdx.x;
  const int w = tid >> 6, lane = tid & 63;
  const int srow = lane >> 3, schunk = (lane & 7) ^ srow;
  const int l15 = lane & 15, lg = lane >> 4;
  const int mb = blockIdx.x >> 1, nb = blockIdx.x & 1;
  const int wr = w >> 1, wc = w & 1;
  f32x4 acc[4][4] = {};
  const unsigned short* Ag = A + (size_t)(mb * 128 + w * 32) * 1024;
  const unsigned short* Bg = Bw + (size_t)(nb * 128 + w * 32) * 1024;
  for (int kt = 0; kt < 16; ++kt) {
    const int k0 = kt * 64;
    __syncthreads();
#pragma unroll
    for (int q = 0; q < 4; ++q) {
      gl_lds16(Ag + (size_t)(q * 8 + srow) * 1024 + k0 + schunk * 8,
               (char*)As + (w * 32 + q * 8) * 128);
      gl_lds16(Bg + (size_t)(q * 8 + srow) * 1024 + k0 + schunk * 8,
               (char*)Bs + (w * 32 + q * 8) * 128);
    }
    __syncthreads();
#pragma unroll
    for (int kk = 0; kk < 2; ++kk) {
      bf16x8 a[4], b[4];
#pragma unroll
      for (int mi = 0; mi < 4; ++mi) {
        int rl = wr * 64 + mi * 16 + l15;
        int slot = (kk * 4 + lg) ^ (rl & 7);
        a[mi] = *(const bf16x8*)(As + rl * 64 + slot * 8);
      }
#pragma unroll
      for (int g = 0; g < 4; ++g) {
        int cl = g * 32 + wc * 16 + l15;
        int slot = (kk * 4 + lg) ^ (cl & 7);
        b[g] = *(const bf16x8*)(Bs + cl * 64 + slot * 8);
      }
#pragma unroll
      for (int mi = 0; mi < 4; ++mi)
#pragma unroll
        for (int g = 0; g < 4; ++g)
          acc[mi][g] = __builtin_amdgcn_mfma_f32_16x16x32_bf16(
              a[mi], b[g], acc[mi][g], 0, 0, 0);
    }
  }
  const int tf = mb >> 3;  // frame index
  float s[4] = {0, 0, 0, 0}, ss[4] = {0, 0, 0, 0};
#pragma unroll
  for (int mi = 0; mi < 4; ++mi)
#pragma unroll
    for (int g = 0; g < 4; ++g) {
      int d = nb * 128 + g * 32 + wc * 16 + l15;
      float bb = bias[d];
#pragma unroll
      for (int i = 0; i < 4; ++i) {
        int row = mb * 128 + wr * 64 + mi * 16 + lg * 4 + i;
        float v = acc[mi][g][i] + bb;
        out[(size_t)row * 256 + d] = v;
        s[g] += v; ss[g] += v * v;
      }
    }
#pragma unroll
  for (int g = 0; g < 4; ++g) {
    s[g] += __shfl_xor(s[g], 16);  s[g] += __shfl_xor(s[g], 32);
    ss[g] += __shfl_xor(ss[g], 16); ss[g] += __shfl_xor(ss[g], 32);
  }
  if (lg == 0) {
#pragma unroll
    for (int g = 0; g < 4; ++g) {
      int d = nb * 128 + g * 32 + wc * 16 + l15;
      atomicAdd(&sumv[tf * 256 + d], s[g]);
      atomicAdd(&sumsq[tf * 256 + d], ss[g]);
    }
  }
}

// ---------------- plain 128x128 GEMM (W_ih @ W_lin precompute) ----------------
__global__ __launch_bounds__(256) void gemm128(
    const unsigned short* __restrict__ A, const unsigned short* __restrict__ B,
    float* __restrict__ C, int K, int nT)
{
  __shared__ __align__(16) unsigned short As[128 * 64];
  __shared__ __align__(16) unsigned short Bs[128 * 64];
  const int tid = threadIdx.x;
  const int w = tid >> 6, lane = tid & 63;
  const int srow = lane >> 3, schunk = (lane & 7) ^ srow;
  const int l15 = lane & 15, lg = lane >> 4;
  const int mb = blockIdx.x / nT, nb = blockIdx.x % nT;
  const int wr = w >> 1, wc = w & 1;
  const int N = nT * 128;
  f32x4 acc[4][4] = {};
  const unsigned short* Ag = A + (size_t)(mb * 128 + w * 32) * K;
  const unsigned short* Bg = B + (size_t)(nb * 128 + w * 32) * K;
  for (int kt = 0; kt < (K >> 6); ++kt) {
    const int k0 = kt * 64;
    __syncthreads();
#pragma unroll
    for (int q = 0; q < 4; ++q) {
      gl_lds16(Ag + (size_t)(q * 8 + srow) * K + k0 + schunk * 8,
               (char*)As + (w * 32 + q * 8) * 128);
      gl_lds16(Bg + (size_t)(q * 8 + srow) * K + k0 + schunk * 8,
               (char*)Bs + (w * 32 + q * 8) * 128);
    }
    __syncthreads();
#pragma unroll
    for (int kk = 0; kk < 2; ++kk) {
      bf16x8 a[4], b[4];
#pragma unroll
      for (int mi = 0; mi < 4; ++mi) {
        int rl = wr * 64 + mi * 16 + l15;
        int slot = (kk * 4 + lg) ^ (rl & 7);
        a[mi] = *(const bf16x8*)(As + rl * 64 + slot * 8);
      }
#pragma unroll
      for (int g = 0; g < 4; ++g) {
        int cl = g * 32 + wc * 16 + l15;
        int slot = (kk * 4 + lg) ^ (cl & 7);
        b[g] = *(const bf16x8*)(Bs + cl * 64 + slot * 8);
      }
#pragma unroll
      for (int mi = 0; mi < 4; ++mi)
#pragma unroll
        for (int g = 0; g < 4; ++g)
          acc[mi][g] = __builtin_amdgcn_mfma_f32_16x16x32_bf16(
              a[mi], b[g], acc[mi][g], 0, 0, 0);
    }
  }
#pragma unroll
  for (int mi = 0; mi < 4; ++mi)
#pragma unroll
    for (int g = 0; g < 4; ++g)
#pragma unroll
      for (int i = 0; i < 4; ++i)
        C[(size_t)(mb * 128 + wr * 64 + mi * 16 + lg * 4 + i) * N + nb * 128 +
          g * 32 + wc * 16 + l15] = acc[mi][g][i];
}

// ---------------- small prep kernels ----------------
__global__ void castall(const float* __restrict__ x, const float* __restrict__ wih,
                        const float* __restrict__ wlin, unsigned short* __restrict__ xb,
                        unsigned short* __restrict__ wihb, unsigned short* __restrict__ wlb) {
  int i = blockIdx.x * 256 + threadIdx.x;  // grid covers 786432
  if (i < 262144) { xb[i] = f2b(x[i]); wlb[i] = f2b(wlin[i]); }
  if (i < 786432) wihb[i] = f2b(wih[i]);
}

// W_lin (256x1024) -> bf16 transpose (1024x256)
__global__ void tcast(const float* __restrict__ in, unsigned short* __restrict__ out) {
  __shared__ float t[32][33];
  int i0 = blockIdx.x * 32, d0 = blockIdx.y * 32;
  for (int r = threadIdx.y; r < 32; r += 8)
    t[r][threadIdx.x] = in[(size_t)(d0 + r) * 1024 + i0 + threadIdx.x];
  __syncthreads();
  for (int r = threadIdx.y; r < 32; r += 8)
    out[(size_t)(i0 + r) * 256 + d0 + threadIdx.x] = f2b(t[threadIdx.x][r]);
}

// Build W_big (n-major [4096][1024], gate-permuted for 64-col wave tiles)
// col layout: jt(5b) | ch(1b) | gate(2b) | c0(4b); j = jt*32 + ch*16 + c0
__global__ void asmWp(const float* __restrict__ CMT, const float* __restrict__ Whh,
                      unsigned short* __restrict__ Wp) {
  int col = blockIdx.x;
  int jt = col >> 7, L = col & 127;
  int ch = L >> 6, gate = (L >> 4) & 3, c0 = L & 15;
  int j = jt * 32 + ch * 16 + c0;
  const float* s1;
  const float* s2 = nullptr;
  if (gate == 0)      { s1 = CMT + (size_t)j * 1024;          s2 = Whh + (size_t)j * 1024; }
  else if (gate == 1) { s1 = CMT + (size_t)(1024 + j) * 1024; s2 = Whh + (size_t)(1024 + j) * 1024; }
  else if (gate == 2) { s1 = CMT + (size_t)(2048 + j) * 1024; }
  else                { s1 = Whh + (size_t)(2048 + j) * 1024; }
  unsigned short* dst = Wp + (size_t)col * 1024;
  for (int k = threadIdx.x; k < 1024; k += 256) {
    float v = s1[k] + (s2 ? s2[k] : 0.0f);
    dst[k] = f2b(v);
  }
}

// Step-0 weights: permuted W_ih.T (n-major [4096][256]), h_n group = 0
__global__ void asmWp0(const float* __restrict__ Wih, unsigned short* __restrict__ Wp0) {
  int col = blockIdx.x;
  int jt = col >> 7, L = col & 127;
  int ch = L >> 6, gate = (L >> 4) & 3, c0 = L & 15;
  int j = jt * 32 + ch * 16 + c0;
  int d = threadIdx.x;  // 256
  float v = 0.0f;
  if (gate < 3) v = Wih[(size_t)(gate * 1024 + j) * 256 + d];
  Wp0[(size_t)col * 256 + d] = f2b(v);
}

__global__ void biask(const float* __restrict__ Wih, const float* __restrict__ bih,
                      const float* __restrict__ bhh, const float* __restrict__ blin,
                      float* __restrict__ cbig, float* __restrict__ c0) {
  int j = blockIdx.x * 256 + threadIdx.x;
  if (j >= 1024) return;
  float bli[3];
  for (int g = 0; g < 3; ++g) {
    int gg = g * 1024 + j;
    float s = bih[gg];
    const float* wrow = Wih + (size_t)gg * 256;
    for (int d = 0; d < 256; ++d) s += blin[d] * wrow[d];
    bli[g] = s;
  }
  cbig[j] = bli[0] + bhh[j];
  cbig[1024 + j] = bli[1] + bhh[1024 + j];
  cbig[2048 + j] = bli[2];
  cbig[3072 + j] = bhh[2048 + j];
  c0[j] = bih[j] + bhh[j];
  c0[1024 + j] = bih[1024 + j] + bhh[1024 + j];
  c0[2048 + j] = bih[2048 + j];
  c0[3072 + j] = bhh[2048 + j];
}

// ---------------- BatchNorm finalize + normalize ----------------
__global__ void bnfin(const float* __restrict__ sv, const float* __restrict__ sq,
                      float* __restrict__ mean, float* __restrict__ rstd) {
  int i = blockIdx.x * 256 + threadIdx.x;  // 32768
  float m = sv[i] * (1.0f / 1024.0f);
  float var = sq[i] * (1.0f / 1024.0f) - m * m;
  mean[i] = m;
  rstd[i] = rsqrtf(var + 1e-5f);
}

__global__ void bnnorm(float* __restrict__ o, const float* __restrict__ mean,
                       const float* __restrict__ rstd) {
  size_t base = ((size_t)blockIdx.x * 256 + threadIdx.x) * 4;  // exact: 32768*256*4
  int t = (int)(base >> 18);
  int d = (int)(base & 255);
  float4 v = *(float4*)(o + base);
  const float* mp = mean + t * 256 + d;
  const float* rp = rstd + t * 256 + d;
  float4 r;
  r.x = (v.x - mp[0]) * rp[0];
  r.y = (v.y - mp[1]) * rp[1];
  r.z = (v.z - mp[2]) * rp[2];
  r.w = (v.w - mp[3]) * rp[3];
  *(float4*)(o + base) = r;
}

// ---------------- launch ----------------
extern "C" void kernel_launch(void* const* d_in, const int* in_sizes, int n_in,
                              void* d_out, int out_size, void* d_ws, size_t ws_size,
                              hipStream_t stream) {
  (void)in_sizes; (void)n_in; (void)out_size; (void)ws_size;
  const float* x    = (const float*)d_in[0];
  const float* h0   = (const float*)d_in[1];
  const float* Wih  = (const float*)d_in[2];
  const float* Whh  = (const float*)d_in[3];
  const float* bih  = (const float*)d_in[4];
  const float* bhh  = (const float*)d_in[5];
  const float* Wlin = (const float*)d_in[6];
  const float* blin = (const float*)d_in[7];
  float* out = (float*)d_out;

  char* ws = (char*)d_ws;
  size_t off = 0;
  auto alloc = [&](size_t bytes) {
    char* p = ws + off;
    off += (bytes + 255) & ~(size_t)255;
    return p;
  };
  unsigned short* WP   = (unsigned short*)alloc(4096ull * 1024 * 2);
  unsigned short* WP0  = (unsigned short*)alloc(4096ull * 256 * 2);
  unsigned short* WIHB = (unsigned short*)alloc(3072ull * 256 * 2);
  unsigned short* WLT  = (unsigned short*)alloc(1024ull * 256 * 2);
  unsigned short* WLB  = (unsigned short*)alloc(256ull * 1024 * 2);
  unsigned short* XB   = (unsigned short*)alloc(1024ull * 256 * 2);
  float* CMT  = (float*)alloc(3072ull * 1024 * 4);
  float* CBIG = (float*)alloc(4096 * 4);
  float* C0   = (float*)alloc(4096 * 4);
  unsigned short* HH  = (unsigned short*)alloc(128ull * 1024 * 1024 * 2);
  float* SUMV = (float*)alloc(128 * 256 * 4);
  float* SUMSQ= (float*)alloc(128 * 256 * 4);
  float* MEAN = (float*)alloc(128 * 256 * 4);
  float* RSTD = (float*)alloc(128 * 256 * 4);
  unsigned int* BAR = (unsigned int*)alloc(4096);

  (void)hipMemsetAsync(BAR, 0, 4096, stream);
  (void)hipMemsetAsync(SUMV, 0, 2 * 128 * 256 * 4, stream);  // SUMV+SUMSQ contiguous

  // precompute: casts, W_lin transpose, C_MT = W_ih @ W_lin, fused weights, biases
  castall<<<3072, 256, 0, stream>>>(x, Wih, Wlin, XB, WIHB, WLB);
  tcast<<<dim3(32, 8), dim3(32, 8), 0, stream>>>(Wlin, WLT);
  gemm128<<<192, 256, 0, stream>>>(WIHB, WLT, CMT, 256, 8);
  asmWp<<<4096, 256, 0, stream>>>(CMT, Whh, WP);
  asmWp0<<<4096, 256, 0, stream>>>(Wih, WP0);
  biask<<<4, 256, 0, stream>>>(Wih, bih, bhh, blin, CBIG, C0);

  // all 128 recurrence steps in one persistent kernel (512 blocks, 2/CU)
  gru_persist<<<512, 256, 0, stream>>>(XB, WP0, WP, C0, CBIG, h0, HH, BAR);

  // deferred frame outputs + fused BN partial sums
  outgemm<<<2048, 256, 0, stream>>>(HH, WLB, blin, out, SUMV, SUMSQ);

  // BatchNorm1d (training stats), in-place on d_out
  bnfin<<<128, 256, 0, stream>>>(SUMV, SUMSQ, MEAN, RSTD);
  bnnorm<<<32768, 256, 0, stream>>>(out, MEAN, RSTD);
}